// Round 1
// baseline (9937.012 us; speedup 1.0000x reference)
//
#include <hip/hip_runtime.h>
#include <cmath>

#define SDIM 64
#define BDIM 64
#define KDIM 512
#define HDIM 512
#define EDIM 512
#define ADIM 512
#define VDIM 32000
#define TSTEPS 32

// ---------------- init: h0 (transposed), x0 = emb[SOS], inv_sum = 1 ----------------
__global__ __launch_bounds__(256) void k_init(const float* __restrict__ efs,
                                              const float* __restrict__ emb,
                                              float* __restrict__ hA,
                                              float* __restrict__ xT,
                                              float* __restrict__ hS,
                                              float* __restrict__ inv_sum) {
  int idx = blockIdx.x * 256 + threadIdx.x;
  if (idx < HDIM * BDIM) {
    int i = idx >> 6, b = idx & 63;
    float h0 = efs[b * HDIM + i];
    hA[idx] = h0;
    hS[idx] = h0;
    xT[idx] = emb[1 * EDIM + i];   // SOS = 1
  }
  if (idx < BDIM) inv_sum[idx] = 1.0f;
}

// ---------------- keys_proj = enc(4096x512) @ Wk(512x512), one-time ----------------
__global__ __launch_bounds__(256) void k_keysproj(const float* __restrict__ enc,
                                                  const float* __restrict__ Wk,
                                                  float* __restrict__ kp) {
  __shared__ float As[16][65];
  __shared__ float Bs[16][64];
  int m0 = blockIdx.x * 64;
  int n0 = blockIdx.y * 64;
  int tid = threadIdx.x;
  int tm = tid >> 4, tn = tid & 15;
  float acc[4][4] = {};
  for (int k0 = 0; k0 < KDIM; k0 += 16) {
    for (int l = tid; l < 1024; l += 256) {
      int m = l >> 4, kk = l & 15;
      As[kk][m] = enc[(size_t)(m0 + m) * KDIM + k0 + kk];
    }
    for (int l = tid; l < 1024; l += 256) {
      int kk = l >> 6, n = l & 63;
      Bs[kk][n] = Wk[(size_t)(k0 + kk) * ADIM + n0 + n];
    }
    __syncthreads();
#pragma unroll
    for (int kk = 0; kk < 16; ++kk) {
      float a[4], w[4];
#pragma unroll
      for (int i = 0; i < 4; ++i) a[i] = As[kk][tm * 4 + i];
#pragma unroll
      for (int j = 0; j < 4; ++j) w[j] = Bs[kk][tn * 4 + j];
#pragma unroll
      for (int i = 0; i < 4; ++i)
#pragma unroll
        for (int j = 0; j < 4; ++j) acc[i][j] += a[i] * w[j];
    }
    __syncthreads();
  }
  for (int i = 0; i < 4; ++i)
    for (int j = 0; j < 4; ++j)
      kp[(size_t)(m0 + tm * 4 + i) * ADIM + n0 + tn * 4 + j] = acc[i][j];
}

// ---------------- qW^T[a][b] = sum_h Wq[h][a] * hT[h][b] ----------------
__device__ __forceinline__ void qw_core(int a0, int lane,
                                        const float* __restrict__ hT,
                                        const float* __restrict__ Wq,
                                        float* __restrict__ qWT) {
  float t0 = 0, t1 = 0, t2 = 0, t3 = 0;
  for (int h0 = 0; h0 < HDIM; h0 += 128) {
    float c0 = 0, c1 = 0, c2 = 0, c3 = 0;
    for (int h = h0; h < h0 + 128; ++h) {
      float hv = hT[h * 64 + lane];
      const float4 w = *(const float4*)(Wq + (size_t)h * ADIM + a0);
      c0 += w.x * hv; c1 += w.y * hv; c2 += w.z * hv; c3 += w.w * hv;
    }
    t0 += c0; t1 += c1; t2 += c2; t3 += c3;
  }
  qWT[(a0 + 0) * 64 + lane] = t0;
  qWT[(a0 + 1) * 64 + lane] = t1;
  qWT[(a0 + 2) * 64 + lane] = t2;
  qWT[(a0 + 3) * 64 + lane] = t3;
}

__global__ __launch_bounds__(256) void k_qw0(const float* __restrict__ hT,
                                             const float* __restrict__ Wq,
                                             float* __restrict__ qWT) {
  int gw = blockIdx.x * 4 + (threadIdx.x >> 6);
  int lane = threadIdx.x & 63;
  int a0 = __builtin_amdgcn_readfirstlane(gw * 4);
  qw_core(a0, lane, hT, Wq, qWT);
}

// ---------------- attention: scores -> softmax(S) -> ctx (one block per b) ----------------
__global__ __launch_bounds__(256) void k_attn(const float* __restrict__ kp,
                                              const float* __restrict__ enc,
                                              const float* __restrict__ qWT,
                                              const float* __restrict__ vatt,
                                              float* __restrict__ cT) {
  int b = blockIdx.x;
  int tid = threadIdx.x;
  __shared__ float qw[ADIM];
  __shared__ float va[ADIM];
  __shared__ float scp[SDIM][4];
  __shared__ float attn[SDIM];
  for (int i = tid; i < ADIM; i += 256) { qw[i] = qWT[i * 64 + b]; va[i] = vatt[i]; }
  __syncthreads();
  int s = tid >> 2, q = tid & 3;
  const float* row = kp + (size_t)(s * BDIM + b) * ADIM;
  float p = 0.f;
  for (int it = 0; it < 32; ++it) {
    int a = q * 4 + it * 16;
    float4 kv = *(const float4*)(row + a);
    float4 qv = *(const float4*)(qw + a);
    float4 vv = *(const float4*)(va + a);
    p += vv.x * tanhf(qv.x + kv.x);
    p += vv.y * tanhf(qv.y + kv.y);
    p += vv.z * tanhf(qv.z + kv.z);
    p += vv.w * tanhf(qv.w + kv.w);
  }
  scp[s][q] = p;
  __syncthreads();
  if (tid < 64) {
    float v = (scp[tid][0] + scp[tid][1]) + (scp[tid][2] + scp[tid][3]);
    float m = v;
#pragma unroll
    for (int o = 32; o > 0; o >>= 1) m = fmaxf(m, __shfl_xor(m, o, 64));
    float e = expf(v - m);
    float ssum = e;
#pragma unroll
    for (int o = 32; o > 0; o >>= 1) ssum += __shfl_xor(ssum, o, 64);
    attn[tid] = e / ssum;
  }
  __syncthreads();
  for (int k = tid; k < KDIM; k += 256) {
    float acc = 0.f;
#pragma unroll 4
    for (int s2 = 0; s2 < SDIM; ++s2) acc += attn[s2] * enc[(size_t)(s2 * BDIM + b) * KDIM + k];
    cT[k * 64 + b] = acc;
  }
}

// ---------------- GRU cell: one wave per hidden unit j, lanes = batch ----------------
__global__ __launch_bounds__(256) void k_gru(const float* __restrict__ catT,
                                             const float* __restrict__ hOld,
                                             const float* __restrict__ Wih,
                                             const float* __restrict__ Whh,
                                             const float* __restrict__ bih,
                                             const float* __restrict__ bhh,
                                             float* __restrict__ hNew,
                                             float* __restrict__ hS) {
  int gw = (blockIdx.x * 256 + threadIdx.x) >> 6;
  int lane = threadIdx.x & 63;
  int j = __builtin_amdgcn_readfirstlane(gw);
  const float* xT = catT;
  const float* cT = catT + 1024 * 64;
  const float* wr = Wih + (size_t)j * 1024;
  const float* wz = Wih + (size_t)(512 + j) * 1024;
  const float* wn = Wih + (size_t)(1024 + j) * 1024;
  const float* vr = Whh + (size_t)j * 512;
  const float* vz = Whh + (size_t)(512 + j) * 512;
  const float* vn = Whh + (size_t)(1024 + j) * 512;
  float air = 0, aiz = 0, ain = 0, ahr = 0, ahz = 0, ahn = 0;
  // x part (W_ih columns [0,512))
  for (int i0 = 0; i0 < 512; i0 += 128) {
    float cr = 0, cz = 0, cn = 0;
    for (int i = i0; i < i0 + 128; i += 4) {
      float x0 = xT[(i + 0) * 64 + lane], x1 = xT[(i + 1) * 64 + lane];
      float x2 = xT[(i + 2) * 64 + lane], x3 = xT[(i + 3) * 64 + lane];
      float4 r4 = *(const float4*)(wr + i);
      float4 z4 = *(const float4*)(wz + i);
      float4 n4 = *(const float4*)(wn + i);
      cr += r4.x * x0 + r4.y * x1 + r4.z * x2 + r4.w * x3;
      cz += z4.x * x0 + z4.y * x1 + z4.z * x2 + z4.w * x3;
      cn += n4.x * x0 + n4.y * x1 + n4.z * x2 + n4.w * x3;
    }
    air += cr; aiz += cz; ain += cn;
  }
  // ctx part (W_ih columns [512,1024))
  for (int i0 = 0; i0 < 512; i0 += 128) {
    float cr = 0, cz = 0, cn = 0;
    for (int i = i0; i < i0 + 128; i += 4) {
      float x0 = cT[(i + 0) * 64 + lane], x1 = cT[(i + 1) * 64 + lane];
      float x2 = cT[(i + 2) * 64 + lane], x3 = cT[(i + 3) * 64 + lane];
      float4 r4 = *(const float4*)(wr + 512 + i);
      float4 z4 = *(const float4*)(wz + 512 + i);
      float4 n4 = *(const float4*)(wn + 512 + i);
      cr += r4.x * x0 + r4.y * x1 + r4.z * x2 + r4.w * x3;
      cz += z4.x * x0 + z4.y * x1 + z4.z * x2 + z4.w * x3;
      cn += n4.x * x0 + n4.y * x1 + n4.z * x2 + n4.w * x3;
    }
    air += cr; aiz += cz; ain += cn;
  }
  // h part
  for (int i0 = 0; i0 < 512; i0 += 128) {
    float cr = 0, cz = 0, cn = 0;
    for (int i = i0; i < i0 + 128; i += 4) {
      float h0 = hOld[(i + 0) * 64 + lane], h1 = hOld[(i + 1) * 64 + lane];
      float h2 = hOld[(i + 2) * 64 + lane], h3 = hOld[(i + 3) * 64 + lane];
      float4 r4 = *(const float4*)(vr + i);
      float4 z4 = *(const float4*)(vz + i);
      float4 n4 = *(const float4*)(vn + i);
      cr += r4.x * h0 + r4.y * h1 + r4.z * h2 + r4.w * h3;
      cz += z4.x * h0 + z4.y * h1 + z4.z * h2 + z4.w * h3;
      cn += n4.x * h0 + n4.y * h1 + n4.z * h2 + n4.w * h3;
    }
    ahr += cr; ahz += cz; ahn += cn;
  }
  float gir = air + bih[j], giz = aiz + bih[512 + j], gin = ain + bih[1024 + j];
  float ghr = ahr + bhh[j], ghz = ahz + bhh[512 + j], ghn = ahn + bhh[1024 + j];
  float r = 1.f / (1.f + expf(-(gir + ghr)));
  float z = 1.f / (1.f + expf(-(giz + ghz)));
  float n = tanhf(gin + r * ghn);
  float ho = hOld[j * 64 + lane];
  float hv = (1.f - z) * n + z * ho;
  hNew[j * 64 + lane] = hv;
  hS[j * 64 + lane] = hv;
}

// ---------------- hid = tanh(mlp_in @ W1 + b1) fused with qW for next step ----------------
__global__ __launch_bounds__(256) void k_mlp1_qw(const float* __restrict__ catT,
                                                 const float* __restrict__ W1,
                                                 const float* __restrict__ b1,
                                                 const float* __restrict__ Wq,
                                                 float* __restrict__ hidT,
                                                 float* __restrict__ qWT) {
  int gw = blockIdx.x * 4 + (threadIdx.x >> 6);
  int lane = threadIdx.x & 63;
  if (gw < 128) {
    int j0 = __builtin_amdgcn_readfirstlane(gw * 4);
    float t0 = 0, t1 = 0, t2 = 0, t3 = 0;
    for (int i0 = 0; i0 < 1536; i0 += 128) {
      float c0 = 0, c1 = 0, c2 = 0, c3 = 0;
      for (int i = i0; i < i0 + 128; ++i) {
        float v = catT[i * 64 + lane];
        float4 w = *(const float4*)(W1 + (size_t)i * 512 + j0);
        c0 += w.x * v; c1 += w.y * v; c2 += w.z * v; c3 += w.w * v;
      }
      t0 += c0; t1 += c1; t2 += c2; t3 += c3;
    }
    hidT[(j0 + 0) * 64 + lane] = tanhf(t0 + b1[j0 + 0]);
    hidT[(j0 + 1) * 64 + lane] = tanhf(t1 + b1[j0 + 1]);
    hidT[(j0 + 2) * 64 + lane] = tanhf(t2 + b1[j0 + 2]);
    hidT[(j0 + 3) * 64 + lane] = tanhf(t3 + b1[j0 + 3]);
  } else {
    int a0 = __builtin_amdgcn_readfirstlane((gw - 128) * 4);
    qw_core(a0, lane, catT + 512 * 64, Wq, qWT);
  }
}

// ---------------- logits GEMM (64x32000) + exp + partials; also normalizes prev step ----------------
__global__ __launch_bounds__(256) void k_logits(const float* __restrict__ hidT,
                                                const float* __restrict__ W2,
                                                const float* __restrict__ b2,
                                                float* __restrict__ out,
                                                int t, int tprev,
                                                const float* __restrict__ inv_sum,
                                                float* __restrict__ psum,
                                                float* __restrict__ pmax,
                                                int* __restrict__ pidx) {
  __shared__ float As[32][64];
  __shared__ float Bs[32][128];
  int bid = blockIdx.x;
  int vbase = bid * 128;
  int tid = threadIdx.x;
  int trow = tid >> 5, tcol = tid & 31;
  int m0 = trow * 8, n0 = tcol * 4;

  // phase 0: scale previous step's slice by its 1/sum (exactly the elements this thread owns)
#pragma unroll
  for (int mi = 0; mi < 8; ++mi) {
    int b = m0 + mi;
    float inv = inv_sum[b];
    float4* p = (float4*)(out + (size_t)(b * TSTEPS + tprev) * VDIM + vbase + n0);
    float4 v = *p;
    v.x *= inv; v.y *= inv; v.z *= inv; v.w *= inv;
    *p = v;
  }

  float accT[8][4] = {};
  for (int k0 = 0; k0 < 512; k0 += 32) {
    for (int l = tid; l < 2048; l += 256)
      As[l >> 6][l & 63] = hidT[(k0 + (l >> 6)) * 64 + (l & 63)];
    for (int l = tid; l < 4096; l += 256)
      Bs[l >> 7][l & 127] = W2[(size_t)(k0 + (l >> 7)) * VDIM + vbase + (l & 127)];
    __syncthreads();
    float accC[8][4] = {};
#pragma unroll
    for (int kk = 0; kk < 32; ++kk) {
      float4 a0 = *(const float4*)&As[kk][m0];
      float4 a1 = *(const float4*)&As[kk][m0 + 4];
      float4 w = *(const float4*)&Bs[kk][n0];
      float am[8] = {a0.x, a0.y, a0.z, a0.w, a1.x, a1.y, a1.z, a1.w};
      float wv[4] = {w.x, w.y, w.z, w.w};
#pragma unroll
      for (int mi = 0; mi < 8; ++mi)
#pragma unroll
        for (int ni = 0; ni < 4; ++ni) accC[mi][ni] += am[mi] * wv[ni];
    }
#pragma unroll
    for (int mi = 0; mi < 8; ++mi)
#pragma unroll
      for (int ni = 0; ni < 4; ++ni) accT[mi][ni] += accC[mi][ni];
    __syncthreads();
  }

  float4 bb = *(const float4*)(b2 + vbase + n0);
  float bv[4] = {bb.x, bb.y, bb.z, bb.w};
  float lsum[8], lmax[8];
  int limx[8];
#pragma unroll
  for (int mi = 0; mi < 8; ++mi) {
    int b = m0 + mi;
    float e[4];
    float mx = -__builtin_inff();
    int mix = 0;
#pragma unroll
    for (int ni = 0; ni < 4; ++ni) {
      float lg = accT[mi][ni] + bv[ni];
      float ev = expf(lg);
      e[ni] = ev;
      if (ev > mx) { mx = ev; mix = vbase + n0 + ni; }
    }
    float4 ev4 = {e[0], e[1], e[2], e[3]};
    *(float4*)(out + (size_t)(b * TSTEPS + t) * VDIM + vbase + n0) = ev4;
    lsum[mi] = (e[0] + e[1]) + (e[2] + e[3]);
    lmax[mi] = mx;
    limx[mi] = mix;
  }

  float* redS = &As[0][0];              // 2048 floats
  float* redM = (float*)&Bs[0][0];      // 2048 floats
  int* redI = ((int*)&Bs[0][0]) + 2048; // 2048 ints
#pragma unroll
  for (int mi = 0; mi < 8; ++mi) {
    int b = m0 + mi;
    redS[b * 32 + tcol] = lsum[mi];
    redM[b * 32 + tcol] = lmax[mi];
    redI[b * 32 + tcol] = limx[mi];
  }
  __syncthreads();
  if (tid < 64) {
    float s = 0, mx = -__builtin_inff();
    int mix = 0x7fffffff;
    for (int c = 0; c < 32; ++c) {
      s += redS[tid * 32 + c];
      float v = redM[tid * 32 + c];
      if (v > mx) { mx = v; mix = redI[tid * 32 + c]; }
    }
    psum[tid * 256 + bid] = s;
    pmax[tid * 256 + bid] = mx;
    pidx[tid * 256 + bid] = mix;
  }
}

// ---------------- finish: reduce partials -> inv_sum, argmax -> next token embedding ----------------
__global__ __launch_bounds__(256) void k_finish(const float* __restrict__ psum,
                                                const float* __restrict__ pmax,
                                                const int* __restrict__ pidx,
                                                const float* __restrict__ emb,
                                                float* __restrict__ inv_sum,
                                                float* __restrict__ xT) {
  int b = blockIdx.x, tid = threadIdx.x;
  __shared__ float ssum[256];
  __shared__ float smax[256];
  __shared__ int sidx[256];
  ssum[tid] = (tid < 250) ? psum[b * 256 + tid] : 0.f;
  smax[tid] = (tid < 250) ? pmax[b * 256 + tid] : -__builtin_inff();
  sidx[tid] = (tid < 250) ? pidx[b * 256 + tid] : 0x7fffffff;
  __syncthreads();
  for (int st = 128; st > 0; st >>= 1) {
    if (tid < st) {
      ssum[tid] += ssum[tid + st];
      float v2 = smax[tid + st];
      int i2 = sidx[tid + st];
      if (v2 > smax[tid] || (v2 == smax[tid] && i2 < sidx[tid])) {
        smax[tid] = v2;
        sidx[tid] = i2;
      }
    }
    __syncthreads();
  }
  __shared__ int stok;
  if (tid == 0) {
    inv_sum[b] = 1.0f / ssum[0];
    stok = sidx[0];
  }
  __syncthreads();
  int tok = stok;
  for (int i = tid; i < EDIM; i += 256) xT[i * 64 + b] = emb[(size_t)tok * EDIM + i];
}

// ---------------- final normalization of step T-1 ----------------
__global__ __launch_bounds__(256) void k_norm_last(float* __restrict__ out,
                                                   const float* __restrict__ inv_sum) {
  int idx = blockIdx.x * 256 + threadIdx.x; // 512000 = 64 * 8000
  int b = idx / 8000, v4 = idx % 8000;
  float inv = inv_sum[b];
  float4* p = (float4*)(out + (size_t)(b * TSTEPS + (TSTEPS - 1)) * VDIM) + v4;
  float4 v = *p;
  v.x *= inv; v.y *= inv; v.z *= inv; v.w *= inv;
  *p = v;
}

extern "C" void kernel_launch(void* const* d_in, const int* in_sizes, int n_in,
                              void* d_out, int out_size, void* d_ws, size_t ws_size,
                              hipStream_t stream) {
  const float* enc  = (const float*)d_in[0];
  const float* efs  = (const float*)d_in[1];
  const float* emb  = (const float*)d_in[2];
  const float* Wq   = (const float*)d_in[3];
  const float* Wk   = (const float*)d_in[4];
  const float* vatt = (const float*)d_in[5];
  const float* Wih  = (const float*)d_in[6];
  const float* Whh  = (const float*)d_in[7];
  const float* bih  = (const float*)d_in[8];
  const float* bhh  = (const float*)d_in[9];
  const float* W1   = (const float*)d_in[10];
  const float* b1   = (const float*)d_in[11];
  const float* W2   = (const float*)d_in[12];
  const float* b2   = (const float*)d_in[13];
  float* out = (float*)d_out;

  float* ws = (float*)d_ws;
  float* kp   = ws;               // 2097152 floats
  float* catT = kp + 2097152;     // 98304 (x | h | c, each 512x64, [feat][batch])
  float* hA   = catT + 98304;     // 32768
  float* hB   = hA + 32768;       // 32768
  float* qWT  = hB + 32768;       // 32768
  float* hidT = qWT + 32768;      // 32768
  float* psum = hidT + 32768;     // 16384
  float* pmax = psum + 16384;     // 16384
  int* pidx   = (int*)(pmax + 16384); // 16384
  float* invs = (float*)(pidx + 16384); // 64

  float* xT = catT;
  float* hS = catT + 512 * 64;
  float* cS = catT + 1024 * 64;

  k_init<<<128, 256, 0, stream>>>(efs, emb, hA, xT, hS, invs);
  k_keysproj<<<dim3(64, 8), 256, 0, stream>>>(enc, Wk, kp);
  k_qw0<<<32, 256, 0, stream>>>(hS, Wq, qWT);

  float* hOld = hA;
  float* hNew = hB;
  for (int t = 0; t < TSTEPS; ++t) {
    k_attn<<<64, 256, 0, stream>>>(kp, enc, qWT, vatt, cS);
    k_gru<<<128, 256, 0, stream>>>(catT, hOld, Wih, Whh, bih, bhh, hNew, hS);
    k_mlp1_qw<<<64, 256, 0, stream>>>(catT, W1, b1, Wq, hidT, qWT);
    k_logits<<<250, 256, 0, stream>>>(hidT, W2, b2, out, t, (t == 0 ? 0 : t - 1),
                                      invs, psum, pmax, pidx);
    k_finish<<<64, 256, 0, stream>>>(psum, pmax, pidx, emb, invs, xT);
    float* tmp = hOld; hOld = hNew; hNew = tmp;
  }
  k_norm_last<<<2000, 256, 0, stream>>>(out, invs);
}

// Round 2
// 4856.475 us; speedup vs baseline: 2.0461x; 2.0461x over previous
//
#include <hip/hip_runtime.h>
#include <cmath>

#define SDIM 64
#define BDIM 64
#define KDIM 512
#define HDIM 512
#define EDIM 512
#define ADIM 512
#define VDIM 32000
#define TSTEPS 32

// ---------------- init: h0 (transposed), x0 = emb[SOS], inv_sum = 1 ----------------
__global__ __launch_bounds__(256) void k_init(const float* __restrict__ efs,
                                              const float* __restrict__ emb,
                                              float* __restrict__ hA,
                                              float* __restrict__ xT,
                                              float* __restrict__ inv_sum) {
  int idx = blockIdx.x * 256 + threadIdx.x;
  if (idx < HDIM * BDIM) {
    int i = idx >> 6, b = idx & 63;
    hA[idx] = efs[b * HDIM + i];
    xT[idx] = emb[1 * EDIM + i];   // SOS = 1
  }
  if (idx < BDIM) inv_sum[idx] = 1.0f;
}

// ---------------- build Wg[1536][1536]: rows 0..1023 = W_ih^T, rows 1024..1535 = W_hh^T ----------------
__global__ __launch_bounds__(256) void k_buildWg(const float* __restrict__ Wih,
                                                 const float* __restrict__ Whh,
                                                 float* __restrict__ Wg) {
  __shared__ float t[32][33];
  int k0 = blockIdx.x * 32;   // output row tile (= source column)
  int j0 = blockIdx.y * 32;   // output col tile (= source row)
  const float* src;
  int ldi, scol;
  if (k0 < 1024) { src = Wih; ldi = 1024; scol = k0; }
  else           { src = Whh; ldi = 512;  scol = k0 - 1024; }
  int tid = threadIdx.x;
#pragma unroll
  for (int i = 0; i < 4; ++i) {
    int e = tid + i * 256, r = e >> 5, c = e & 31;
    t[r][c] = src[(size_t)(j0 + r) * ldi + scol + c];
  }
  __syncthreads();
#pragma unroll
  for (int i = 0; i < 4; ++i) {
    int e = tid + i * 256, r = e >> 5, c = e & 31;
    Wg[(size_t)(k0 + r) * 1536 + j0 + c] = t[c][r];
  }
}

// ---------------- keys_proj = enc(4096x512) @ Wk(512x512), one-time ----------------
__global__ __launch_bounds__(256) void k_keysproj(const float* __restrict__ enc,
                                                  const float* __restrict__ Wk,
                                                  float* __restrict__ kp) {
  __shared__ float As[16][65];
  __shared__ float Bs[16][64];
  int m0 = blockIdx.x * 64;
  int n0 = blockIdx.y * 64;
  int tid = threadIdx.x;
  int tm = tid >> 4, tn = tid & 15;
  float acc[4][4] = {};
  for (int k0 = 0; k0 < KDIM; k0 += 16) {
    for (int l = tid; l < 1024; l += 256) {
      int m = l >> 4, kk = l & 15;
      As[kk][m] = enc[(size_t)(m0 + m) * KDIM + k0 + kk];
    }
    for (int l = tid; l < 1024; l += 256) {
      int kk = l >> 6, n = l & 63;
      Bs[kk][n] = Wk[(size_t)(k0 + kk) * ADIM + n0 + n];
    }
    __syncthreads();
#pragma unroll
    for (int kk = 0; kk < 16; ++kk) {
      float a[4], w[4];
#pragma unroll
      for (int i = 0; i < 4; ++i) a[i] = As[kk][tm * 4 + i];
#pragma unroll
      for (int j = 0; j < 4; ++j) w[j] = Bs[kk][tn * 4 + j];
#pragma unroll
      for (int i = 0; i < 4; ++i)
#pragma unroll
        for (int j = 0; j < 4; ++j) acc[i][j] += a[i] * w[j];
    }
    __syncthreads();
  }
  for (int i = 0; i < 4; ++i)
    for (int j = 0; j < 4; ++j)
      kp[(size_t)(m0 + tm * 4 + i) * ADIM + n0 + tn * 4 + j] = acc[i][j];
}

// ---------------- shared GEMM core: C[n][b] (64x64 tile) = sum_{k<512} A_T[k][b] * W[k][n] ----------------
// A: [512][64] k-major; W: pre-offset to (row0, n0), ldw = row stride; Cout: pre-offset to n0*64.
// LDS-staged, register double-buffer prefetch.
__device__ __forceinline__ void gemm512_core(const float* __restrict__ A,
                                             const float* __restrict__ W, int ldw,
                                             float* __restrict__ Cout) {
  __shared__ float As[32][64];
  __shared__ float Ws[32][64];
  int tid = threadIdx.x;
  int tn = tid >> 4, tb = tid & 15;
  float acc[4][4] = {};
  float ra[8], rw[8];
#pragma unroll
  for (int t = 0; t < 8; ++t) {
    int l = tid + t * 256, kk = l >> 6, c = l & 63;
    ra[t] = A[kk * 64 + c];
    rw[t] = W[(size_t)kk * ldw + c];
  }
  for (int k0 = 0; k0 < 512; k0 += 32) {
#pragma unroll
    for (int t = 0; t < 8; ++t) {
      int l = tid + t * 256, kk = l >> 6, c = l & 63;
      As[kk][c] = ra[t];
      Ws[kk][c] = rw[t];
    }
    __syncthreads();
    if (k0 + 32 < 512) {
#pragma unroll
      for (int t = 0; t < 8; ++t) {
        int l = tid + t * 256, kk = l >> 6, c = l & 63;
        ra[t] = A[(k0 + 32 + kk) * 64 + c];
        rw[t] = W[(size_t)(k0 + 32 + kk) * ldw + c];
      }
    }
#pragma unroll
    for (int kk = 0; kk < 32; ++kk) {
      float4 a = *(const float4*)&As[kk][tb * 4];
      float4 w = *(const float4*)&Ws[kk][tn * 4];
      acc[0][0] += w.x * a.x; acc[0][1] += w.x * a.y; acc[0][2] += w.x * a.z; acc[0][3] += w.x * a.w;
      acc[1][0] += w.y * a.x; acc[1][1] += w.y * a.y; acc[1][2] += w.y * a.z; acc[1][3] += w.y * a.w;
      acc[2][0] += w.z * a.x; acc[2][1] += w.z * a.y; acc[2][2] += w.z * a.z; acc[2][3] += w.z * a.w;
      acc[3][0] += w.w * a.x; acc[3][1] += w.w * a.y; acc[3][2] += w.w * a.z; acc[3][3] += w.w * a.w;
    }
    __syncthreads();
  }
#pragma unroll
  for (int i = 0; i < 4; ++i)
#pragma unroll
    for (int j = 0; j < 4; ++j)
      Cout[(tn * 4 + i) * 64 + tb * 4 + j] = acc[i][j];
}

// ---------------- initial qW: qWT[a][b] = sum_h hA[h][b] Wq[h][a]; grid 8 ----------------
__global__ __launch_bounds__(256) void k_qw_only(const float* __restrict__ hA,
                                                 const float* __restrict__ Wq,
                                                 float* __restrict__ qWT) {
  int nt = blockIdx.x;
  gemm512_core(hA, Wq + nt * 64, ADIM, qWT + nt * 64 * 64);
}

// ---------------- gates partials: Gp[s][j][b], s: 0=x, 1=ctx, 2=h; grid 72 ----------------
__global__ __launch_bounds__(256) void k_gates(const float* __restrict__ catT,
                                               const float* __restrict__ hOld,
                                               const float* __restrict__ Wg,
                                               float* __restrict__ Gp) {
  int bid = blockIdx.x;
  int nt = bid / 3, s = bid % 3;
  const float* A = (s == 0) ? catT : (s == 1) ? (catT + 512 * 64) : hOld;
  const float* W = Wg + (size_t)s * 512 * 1536 + nt * 64;
  float* C = Gp + ((size_t)s * 1536 + nt * 64) * 64;
  gemm512_core(A, W, 1536, C);
}

// ---------------- GRU nonlinearity: hNew from Gp + biases + hOld; grid 128 ----------------
__global__ __launch_bounds__(256) void k_gru_nonlin(const float* __restrict__ Gp,
                                                    const float* __restrict__ bih,
                                                    const float* __restrict__ bhh,
                                                    const float* __restrict__ hOld,
                                                    float* __restrict__ hNew) {
  int idx = blockIdx.x * 256 + threadIdx.x;   // 32768
  int u = idx >> 6, b = idx & 63;
  const int S = 1536 * 64;
  float gir = Gp[u * 64 + b] + Gp[S + u * 64 + b];
  float ghr = Gp[2 * S + u * 64 + b];
  float giz = Gp[(512 + u) * 64 + b] + Gp[S + (512 + u) * 64 + b];
  float ghz = Gp[2 * S + (512 + u) * 64 + b];
  float gin = Gp[(1024 + u) * 64 + b] + Gp[S + (1024 + u) * 64 + b];
  float ghn = Gp[2 * S + (1024 + u) * 64 + b];
  float r = 1.f / (1.f + expf(-(gir + bih[u] + ghr + bhh[u])));
  float z = 1.f / (1.f + expf(-(giz + bih[512 + u] + ghz + bhh[512 + u])));
  float n = tanhf(gin + bih[1024 + u] + r * (ghn + bhh[1024 + u]));
  hNew[u * 64 + b] = (1.f - z) * n + z * hOld[u * 64 + b];
}

// ---------------- mlp1 partials Hp[s][n][b] + qW for next step (direct); grid 32 ----------------
__global__ __launch_bounds__(256) void k_mlp1qw(const float* __restrict__ catT,
                                                const float* __restrict__ hNew,
                                                const float* __restrict__ W1,
                                                const float* __restrict__ Wq,
                                                float* __restrict__ Hp,
                                                float* __restrict__ qWT) {
  int bid = blockIdx.x;
  if (bid < 24) {
    int nt = bid / 3, s = bid % 3;
    // mlp_in = [x, h_new, ctx]; W1 row blocks: x=0..511, h=512..1023, ctx=1024..1535
    const float* A = (s == 0) ? catT : (s == 1) ? (catT + 512 * 64) : hNew;
    const float* W = W1 + ((s == 0) ? 0 : (s == 1) ? (size_t)1024 * 512 : (size_t)512 * 512) + nt * 64;
    float* C = Hp + ((size_t)s * 512 + nt * 64) * 64;
    gemm512_core(A, W, 512, C);
  } else {
    int nt = bid - 24;
    gemm512_core(hNew, Wq + nt * 64, ADIM, qWT + nt * 64 * 64);
  }
}

// ---------------- hid reduce: hidT = tanh(sum Hp + b1); grid 128 ----------------
__global__ __launch_bounds__(256) void k_hid_reduce(const float* __restrict__ Hp,
                                                    const float* __restrict__ b1,
                                                    float* __restrict__ hidT) {
  int idx = blockIdx.x * 256 + threadIdx.x;   // 32768
  int n = idx >> 6;
  hidT[idx] = tanhf(Hp[idx] + Hp[32768 + idx] + Hp[65536 + idx] + b1[n]);
}

// ---------------- attention: scores -> softmax(S) -> ctx (one block per b) ----------------
__global__ __launch_bounds__(256) void k_attn(const float* __restrict__ kp,
                                              const float* __restrict__ enc,
                                              const float* __restrict__ qWT,
                                              const float* __restrict__ vatt,
                                              float* __restrict__ cT) {
  int b = blockIdx.x;
  int tid = threadIdx.x;
  __shared__ float qw[ADIM];
  __shared__ float va[ADIM];
  __shared__ float scp[SDIM][4];
  __shared__ float attn[SDIM];
  for (int i = tid; i < ADIM; i += 256) { qw[i] = qWT[i * 64 + b]; va[i] = vatt[i]; }
  __syncthreads();
  int s = tid >> 2, q = tid & 3;
  const float* row = kp + (size_t)(s * BDIM + b) * ADIM;
  float p = 0.f;
  for (int it = 0; it < 32; ++it) {
    int a = q * 4 + it * 16;
    float4 kv = *(const float4*)(row + a);
    float4 qv = *(const float4*)(qw + a);
    float4 vv = *(const float4*)(va + a);
    p += vv.x * tanhf(qv.x + kv.x);
    p += vv.y * tanhf(qv.y + kv.y);
    p += vv.z * tanhf(qv.z + kv.z);
    p += vv.w * tanhf(qv.w + kv.w);
  }
  scp[s][q] = p;
  __syncthreads();
  if (tid < 64) {
    float v = (scp[tid][0] + scp[tid][1]) + (scp[tid][2] + scp[tid][3]);
    float m = v;
#pragma unroll
    for (int o = 32; o > 0; o >>= 1) m = fmaxf(m, __shfl_xor(m, o, 64));
    float e = expf(v - m);
    float ssum = e;
#pragma unroll
    for (int o = 32; o > 0; o >>= 1) ssum += __shfl_xor(ssum, o, 64);
    attn[tid] = e / ssum;
  }
  __syncthreads();
  for (int k = tid; k < KDIM; k += 256) {
    float acc = 0.f;
#pragma unroll 4
    for (int s2 = 0; s2 < SDIM; ++s2) acc += attn[s2] * enc[(size_t)(s2 * BDIM + b) * KDIM + k];
    cT[k * 64 + b] = acc;
  }
}

// ---------------- logits GEMM (64x32000) + exp + partials; also normalizes prev step ----------------
__global__ __launch_bounds__(256) void k_logits(const float* __restrict__ hidT,
                                                const float* __restrict__ W2,
                                                const float* __restrict__ b2,
                                                float* __restrict__ out,
                                                int t, int tprev,
                                                const float* __restrict__ inv_sum,
                                                float* __restrict__ psum,
                                                float* __restrict__ pmax,
                                                int* __restrict__ pidx) {
  __shared__ float As[32][64];
  __shared__ float Bs[32][128];
  int bid = blockIdx.x;
  int vbase = bid * 128;
  int tid = threadIdx.x;
  int trow = tid >> 5, tcol = tid & 31;
  int m0 = trow * 8, n0 = tcol * 4;

  // phase 0: scale previous step's slice by its 1/sum (exactly the elements this thread owns)
#pragma unroll
  for (int mi = 0; mi < 8; ++mi) {
    int b = m0 + mi;
    float inv = inv_sum[b];
    float4* p = (float4*)(out + (size_t)(b * TSTEPS + tprev) * VDIM + vbase + n0);
    float4 v = *p;
    v.x *= inv; v.y *= inv; v.z *= inv; v.w *= inv;
    *p = v;
  }

  float pa[8], pb[16];
#pragma unroll
  for (int tt = 0; tt < 8; ++tt) {
    int l = tid + tt * 256;
    pa[tt] = hidT[(l >> 6) * 64 + (l & 63)];
  }
#pragma unroll
  for (int tt = 0; tt < 16; ++tt) {
    int l = tid + tt * 256;
    pb[tt] = W2[(size_t)(l >> 7) * VDIM + vbase + (l & 127)];
  }

  float accT[8][4] = {};
  for (int k0 = 0; k0 < 512; k0 += 32) {
#pragma unroll
    for (int tt = 0; tt < 8; ++tt) {
      int l = tid + tt * 256;
      As[l >> 6][l & 63] = pa[tt];
    }
#pragma unroll
    for (int tt = 0; tt < 16; ++tt) {
      int l = tid + tt * 256;
      Bs[l >> 7][l & 127] = pb[tt];
    }
    __syncthreads();
    if (k0 + 32 < 512) {
#pragma unroll
      for (int tt = 0; tt < 8; ++tt) {
        int l = tid + tt * 256;
        pa[tt] = hidT[(k0 + 32 + (l >> 6)) * 64 + (l & 63)];
      }
#pragma unroll
      for (int tt = 0; tt < 16; ++tt) {
        int l = tid + tt * 256;
        pb[tt] = W2[(size_t)(k0 + 32 + (l >> 7)) * VDIM + vbase + (l & 127)];
      }
    }
    float accC[8][4] = {};
#pragma unroll
    for (int kk = 0; kk < 32; ++kk) {
      float4 a0 = *(const float4*)&As[kk][m0];
      float4 a1 = *(const float4*)&As[kk][m0 + 4];
      float4 w = *(const float4*)&Bs[kk][n0];
      float am[8] = {a0.x, a0.y, a0.z, a0.w, a1.x, a1.y, a1.z, a1.w};
      float wv[4] = {w.x, w.y, w.z, w.w};
#pragma unroll
      for (int mi = 0; mi < 8; ++mi)
#pragma unroll
        for (int ni = 0; ni < 4; ++ni) accC[mi][ni] += am[mi] * wv[ni];
    }
#pragma unroll
    for (int mi = 0; mi < 8; ++mi)
#pragma unroll
      for (int ni = 0; ni < 4; ++ni) accT[mi][ni] += accC[mi][ni];
    __syncthreads();
  }

  float4 bb = *(const float4*)(b2 + vbase + n0);
  float bv[4] = {bb.x, bb.y, bb.z, bb.w};
  float lsum[8], lmax[8];
  int limx[8];
#pragma unroll
  for (int mi = 0; mi < 8; ++mi) {
    int b = m0 + mi;
    float e[4];
    float mx = -__builtin_inff();
    int mix = 0;
#pragma unroll
    for (int ni = 0; ni < 4; ++ni) {
      float lg = accT[mi][ni] + bv[ni];
      float ev = expf(lg);
      e[ni] = ev;
      if (ev > mx) { mx = ev; mix = vbase + n0 + ni; }
    }
    float4 ev4 = {e[0], e[1], e[2], e[3]};
    *(float4*)(out + (size_t)(b * TSTEPS + t) * VDIM + vbase + n0) = ev4;
    lsum[mi] = (e[0] + e[1]) + (e[2] + e[3]);
    lmax[mi] = mx;
    limx[mi] = mix;
  }

  float* redS = &As[0][0];              // 2048 floats
  float* redM = (float*)&Bs[0][0];      // 2048 floats
  int* redI = ((int*)&Bs[0][0]) + 2048; // 2048 ints
#pragma unroll
  for (int mi = 0; mi < 8; ++mi) {
    int b = m0 + mi;
    redS[b * 32 + tcol] = lsum[mi];
    redM[b * 32 + tcol] = lmax[mi];
    redI[b * 32 + tcol] = limx[mi];
  }
  __syncthreads();
  if (tid < 64) {
    float s = 0, mx = -__builtin_inff();
    int mix = 0x7fffffff;
    for (int c = 0; c < 32; ++c) {
      s += redS[tid * 32 + c];
      float v = redM[tid * 32 + c];
      if (v > mx) { mx = v; mix = redI[tid * 32 + c]; }
    }
    psum[tid * 256 + bid] = s;
    pmax[tid * 256 + bid] = mx;
    pidx[tid * 256 + bid] = mix;
  }
}

// ---------------- finish: reduce partials -> inv_sum, argmax -> next token embedding ----------------
__global__ __launch_bounds__(256) void k_finish(const float* __restrict__ psum,
                                                const float* __restrict__ pmax,
                                                const int* __restrict__ pidx,
                                                const float* __restrict__ emb,
                                                float* __restrict__ inv_sum,
                                                float* __restrict__ xT) {
  int b = blockIdx.x, tid = threadIdx.x;
  __shared__ float ssum[256];
  __shared__ float smax[256];
  __shared__ int sidx[256];
  ssum[tid] = (tid < 250) ? psum[b * 256 + tid] : 0.f;
  smax[tid] = (tid < 250) ? pmax[b * 256 + tid] : -__builtin_inff();
  sidx[tid] = (tid < 250) ? pidx[b * 256 + tid] : 0x7fffffff;
  __syncthreads();
  for (int st = 128; st > 0; st >>= 1) {
    if (tid < st) {
      ssum[tid] += ssum[tid + st];
      float v2 = smax[tid + st];
      int i2 = sidx[tid + st];
      if (v2 > smax[tid] || (v2 == smax[tid] && i2 < sidx[tid])) {
        smax[tid] = v2;
        sidx[tid] = i2;
      }
    }
    __syncthreads();
  }
  __shared__ int stok;
  if (tid == 0) {
    inv_sum[b] = 1.0f / ssum[0];
    stok = sidx[0];
  }
  __syncthreads();
  int tok = stok;
  for (int i = tid; i < EDIM; i += 256) xT[i * 64 + b] = emb[(size_t)tok * EDIM + i];
}

// ---------------- final normalization of step T-1 ----------------
__global__ __launch_bounds__(256) void k_norm_last(float* __restrict__ out,
                                                   const float* __restrict__ inv_sum) {
  int idx = blockIdx.x * 256 + threadIdx.x; // 512000 = 64 * 8000
  int b = idx / 8000, v4 = idx % 8000;
  float inv = inv_sum[b];
  float4* p = (float4*)(out + (size_t)(b * TSTEPS + (TSTEPS - 1)) * VDIM) + v4;
  float4 v = *p;
  v.x *= inv; v.y *= inv; v.z *= inv; v.w *= inv;
  *p = v;
}

extern "C" void kernel_launch(void* const* d_in, const int* in_sizes, int n_in,
                              void* d_out, int out_size, void* d_ws, size_t ws_size,
                              hipStream_t stream) {
  const float* enc  = (const float*)d_in[0];
  const float* efs  = (const float*)d_in[1];
  const float* emb  = (const float*)d_in[2];
  const float* Wq   = (const float*)d_in[3];
  const float* Wk   = (const float*)d_in[4];
  const float* vatt = (const float*)d_in[5];
  const float* Wih  = (const float*)d_in[6];
  const float* Whh  = (const float*)d_in[7];
  const float* bih  = (const float*)d_in[8];
  const float* bhh  = (const float*)d_in[9];
  const float* W1   = (const float*)d_in[10];
  const float* b1   = (const float*)d_in[11];
  const float* W2   = (const float*)d_in[12];
  const float* b2   = (const float*)d_in[13];
  float* out = (float*)d_out;

  float* ws = (float*)d_ws;
  float* kp   = ws;                   // 2,097,152
  float* Wg   = kp + 2097152;         // 2,359,296 (combined W_ih^T | W_hh^T)
  float* catT = Wg + 2359296;         // 65,536 (x rows 0..511 | ctx rows 512..1023)
  float* hA   = catT + 65536;         // 32,768
  float* hB   = hA + 32768;           // 32,768
  float* qWT  = hB + 32768;           // 32,768
  float* hidT = qWT + 32768;          // 32,768
  float* Gp   = hidT + 32768;         // 294,912 (3 x 1536 x 64)
  float* Hp   = Gp + 294912;          // 98,304  (3 x 512 x 64)
  float* psum = Hp + 98304;           // 16,384
  float* pmax = psum + 16384;         // 16,384
  int* pidx   = (int*)(pmax + 16384); // 16,384
  float* invs = (float*)(pidx + 16384); // 64

  float* xT = catT;
  float* cS = catT + 512 * 64;

  k_init<<<128, 256, 0, stream>>>(efs, emb, hA, xT, invs);
  k_buildWg<<<dim3(48, 48), 256, 0, stream>>>(Wih, Whh, Wg);
  k_keysproj<<<dim3(64, 8), 256, 0, stream>>>(enc, Wk, kp);
  k_qw_only<<<8, 256, 0, stream>>>(hA, Wq, qWT);

  float* hOld = hA;
  float* hNew = hB;
  for (int t = 0; t < TSTEPS; ++t) {
    k_attn<<<64, 256, 0, stream>>>(kp, enc, qWT, vatt, cS);
    k_gates<<<72, 256, 0, stream>>>(catT, hOld, Wg, Gp);
    k_gru_nonlin<<<128, 256, 0, stream>>>(Gp, bih, bhh, hOld, hNew);
    k_mlp1qw<<<32, 256, 0, stream>>>(catT, hNew, W1, Wq, Hp, qWT);
    k_hid_reduce<<<128, 256, 0, stream>>>(Hp, b1, hidT);
    k_logits<<<250, 256, 0, stream>>>(hidT, W2, b2, out, t, (t == 0 ? 0 : t - 1),
                                      invs, psum, pmax, pidx);
    k_finish<<<64, 256, 0, stream>>>(psum, pmax, pidx, emb, invs, xT);
    float* tmp = hOld; hOld = hNew; hNew = tmp;
  }
  k_norm_last<<<2000, 256, 0, stream>>>(out, invs);
}